// Round 1
// baseline (243.156 us; speedup 1.0000x reference)
//
#include <hip/hip_runtime.h>
#include <hip/hip_bf16.h>

#define B_ 1024
#define H_ 512
#define N_ (B_ * 64)
#define FFN_ 2048
#define OUT_ 86

__device__ __forceinline__ float wred_sum(float v) {
#pragma unroll
  for (int m = 32; m; m >>= 1) v += __shfl_xor(v, m);
  return v;
}
__device__ __forceinline__ float wred_max(float v) {
#pragma unroll
  for (int m = 32; m; m >>= 1) v = fmaxf(v, __shfl_xor(v, m));
  return v;
}

// d[k] = sum_h w_i_w[k][h]*prj_b[h]; e[j] = sum_h prj_w[j][h]*w_b[h]; c0 = w_b . prj_b
__global__ void k_prep(const float* __restrict__ w_i_w, const float* __restrict__ w_i_b,
                       const float* __restrict__ prj_w, const float* __restrict__ prj_b,
                       float* __restrict__ dv, float* __restrict__ ev, float* __restrict__ c0) {
  int b = blockIdx.x, l = threadIdx.x;
  float s = 0.f;
  if (b < 512) {
    for (int h = l; h < H_; h += 64) s += w_i_w[b * H_ + h] * prj_b[h];
    s = wred_sum(s);
    if (l == 0) dv[b] = s;
  } else if (b < 1024) {
    int j = b - 512;
    for (int h = l; h < H_; h += 64) s += prj_w[j * H_ + h] * w_i_b[h];
    s = wred_sum(s);
    if (l == 0) ev[j] = s;
  } else {
    for (int h = l; h < H_; h += 64) s += w_i_b[h] * prj_b[h];
    s = wred_sum(s);
    if (l == 0) c0[0] = s;
  }
}

// c_left[b] = ro[b].e + c0 (side 0); c_right[b] = lo[b].e + c0 (side 1)
__global__ void k_cvec(const float* __restrict__ ro, const float* __restrict__ lo,
                       const float* __restrict__ ev, const float* __restrict__ c0,
                       float* __restrict__ cL, float* __restrict__ cR) {
  int b = blockIdx.x, side = blockIdx.y, l = threadIdx.x;
  const float* x = side ? lo : ro;
  float s = 0.f;
  for (int j = l; j < H_; j += 64) s += x[b * H_ + j] * ev[j];
  s = wred_sum(s);
  if (l == 0) (side ? cR : cL)[b] = s + c0[0];
}

// Generic f32 tiled GEMM: C[M][N] = A[M][K] @ op(B)  (+bias, +relu)
// BT=true : B is [N][K] row-major (NT);  BT=false : B is [K][N] row-major (NN)
template <bool BT, bool BIAS, bool RELU>
__global__ __launch_bounds__(256) void gemm64(const float* __restrict__ A, const float* __restrict__ Bm,
                                              const float* __restrict__ bias, float* __restrict__ C,
                                              int M, int N, int K) {
  __shared__ float As[16][68];
  __shared__ float Bs[16][68];
  const int bm = blockIdx.x * 64, bn = blockIdx.y * 64;
  const int t = threadIdx.x;
  const int tx = t & 15, ty = t >> 4;
  float acc[4][4] = {};
  for (int k0 = 0; k0 < K; k0 += 16) {
#pragma unroll
    for (int i = 0; i < 4; i++) {
      int m = (t >> 4) + i * 16;
      As[t & 15][m] = A[(size_t)(bm + m) * K + k0 + (t & 15)];
    }
    if (BT) {
#pragma unroll
      for (int i = 0; i < 4; i++) {
        int n = (t >> 4) + i * 16;
        Bs[t & 15][n] = Bm[(size_t)(bn + n) * K + k0 + (t & 15)];
      }
    } else {
#pragma unroll
      for (int i = 0; i < 4; i++) {
        int kk = (t >> 6) + i * 4;
        Bs[kk][t & 63] = Bm[(size_t)(k0 + kk) * N + bn + (t & 63)];
      }
    }
    __syncthreads();
#pragma unroll
    for (int kk = 0; kk < 16; kk++) {
      float4 av = *(const float4*)&As[kk][ty * 4];
      float4 bv = *(const float4*)&Bs[kk][tx * 4];
      float a_[4] = {av.x, av.y, av.z, av.w};
      float b_[4] = {bv.x, bv.y, bv.z, bv.w};
#pragma unroll
      for (int i = 0; i < 4; i++)
#pragma unroll
        for (int j = 0; j < 4; j++) acc[i][j] += a_[i] * b_[j];
    }
    __syncthreads();
  }
#pragma unroll
  for (int i = 0; i < 4; i++) {
    int m = bm + ty * 4 + i;
    float4 v;
    float tmp[4];
#pragma unroll
    for (int j = 0; j < 4; j++) {
      float x = acc[i][j];
      if (BIAS) x += bias[bn + tx * 4 + j];
      if (RELU) x = fmaxf(x, 0.f);
      tmp[j] = x;
    }
    v.x = tmp[0]; v.y = tmp[1]; v.z = tmp[2]; v.w = tmp[3];
    *(float4*)&C[(size_t)m * N + bn + tx * 4] = v;
  }
}

// Per-(molecule, side): scores = softmax(atom . u[b] + c[b]) over 64 atoms; p[b] = sum_i scores[i]*atom[i]
// One global pass: the 64x512 tile lives in registers (8 waves x 8 atoms x 8 cols/lane).
__global__ __launch_bounds__(512) void k_atoms(const float* __restrict__ atomL, const float* __restrict__ atomR,
                                               const float* __restrict__ uL, const float* __restrict__ uR,
                                               const float* __restrict__ cL, const float* __restrict__ cR,
                                               float* __restrict__ scoresL, float* __restrict__ scoresR,
                                               float* __restrict__ pL, float* __restrict__ pR) {
  const int b = blockIdx.x, side = blockIdx.y;
  const float* __restrict__ atom = side ? atomR : atomL;
  const float* __restrict__ u = side ? uR : uL;
  const float cb = (side ? cR : cL)[b];
  float* __restrict__ scores = side ? scoresR : scoresL;
  float* __restrict__ p = side ? pR : pL;

  const int t = threadIdx.x, wave = t >> 6, lane = t & 63;
  const int colA = lane * 4, colB = 256 + lane * 4;

  __shared__ float s_lds[64];
  __shared__ float pp_lds[8][512];

  float ur[8];
  *(float4*)&ur[0] = *(const float4*)&u[(size_t)b * H_ + colA];
  *(float4*)&ur[4] = *(const float4*)&u[(size_t)b * H_ + colB];

  float a[8][8];
#pragma unroll
  for (int ai = 0; ai < 8; ai++) {
    const size_t row = (size_t)b * 64 + wave * 8 + ai;
    *(float4*)&a[ai][0] = *(const float4*)&atom[row * H_ + colA];
    *(float4*)&a[ai][4] = *(const float4*)&atom[row * H_ + colB];
    float dot = 0.f;
#pragma unroll
    for (int j = 0; j < 8; j++) dot += a[ai][j] * ur[j];
    dot = wred_sum(dot);
    if (lane == 0) s_lds[wave * 8 + ai] = dot + cb;
  }
  __syncthreads();
  if (wave == 0) {
    float s = s_lds[lane];
    float mx = wred_max(s);
    float e = expf(s - mx);
    float z = wred_sum(e);
    float w = e / z;
    s_lds[lane] = w;
    scores[(size_t)b * 64 + lane] = w;
  }
  __syncthreads();
  float pp[8] = {};
#pragma unroll
  for (int ai = 0; ai < 8; ai++) {
    float w = s_lds[wave * 8 + ai];
#pragma unroll
    for (int j = 0; j < 8; j++) pp[j] += w * a[ai][j];
  }
#pragma unroll
  for (int j = 0; j < 4; j++) {
    pp_lds[wave][colA + j] = pp[j];
    pp_lds[wave][colB + j] = pp[4 + j];
  }
  __syncthreads();
  float s = 0.f;
#pragma unroll
  for (int w2 = 0; w2 < 8; w2++) s += pp_lds[w2][t];
  p[(size_t)b * H_ + t] = s;
}

// perturbation + pair assembly
__global__ __launch_bounds__(512) void k_pert(const float* __restrict__ lo, const float* __restrict__ ro,
                                              const float* __restrict__ noise,
                                              const float* __restrict__ pL, const float* __restrict__ pR,
                                              float* __restrict__ h_out, float* __restrict__ h_pert,
                                              float* __restrict__ pair) {
  const int b = blockIdx.x, t = threadIdx.x;
  float nv = noise[(size_t)b * H_ + t];
  float sq = nv * nv;
  sq = wred_sum(sq);
  __shared__ float red[8];
  if ((t & 63) == 0) red[t >> 6] = sq;
  __syncthreads();
  float tot = 0.f;
#pragma unroll
  for (int i = 0; i < 8; i++) tot += red[i];
  float nrm = fmaxf(sqrtf(tot), 1e-12f);
  float nn = nv / nrm * 0.1f;
  float h = ro[(size_t)b * H_ + t] * pL[(size_t)b * H_ + t];
  float tt = lo[(size_t)b * H_ + t] * pR[(size_t)b * H_ + t];
  float sh = (h > 0.f) ? 1.f : ((h < 0.f) ? -1.f : 0.f);
  float st = (tt > 0.f) ? 1.f : ((tt < 0.f) ? -1.f : 0.f);
  float hp = h + sh * nn;
  float tp = tt + st * nn;
  h_out[(size_t)b * H_ + t] = h;
  h_pert[(size_t)b * H_ + t] = hp;
  pair[(size_t)b * 1024 + t] = hp;
  pair[(size_t)b * 1024 + 512 + t] = tp;
}

__global__ void k_w2t(const float* __restrict__ W2, float* __restrict__ W2t) {
  int idx = blockIdx.x * 256 + threadIdx.x;
  if (idx < OUT_ * FFN_) {
    int n = idx / FFN_, k = idx % FFN_;
    W2t[idx] = W2[(size_t)k * OUT_ + n];
  }
}

// out[b][n] = hid[b] . W2t[n] + b2[n]; 2 rows per block, wave-per-n-group, k-parallel lanes
__global__ __launch_bounds__(256) void k_ffn2(const float* __restrict__ hid, const float* __restrict__ W2t,
                                              const float* __restrict__ b2, float* __restrict__ out) {
  const int b0 = blockIdx.x * 2;
  const int t = threadIdx.x, wave = t >> 6, lane = t & 63;
  float4 h0[8], h1[8];
  const float* r0 = hid + (size_t)b0 * FFN_;
#pragma unroll
  for (int j = 0; j < 8; j++) {
    h0[j] = *(const float4*)&r0[lane * 4 + j * 256];
    h1[j] = *(const float4*)&r0[FFN_ + lane * 4 + j * 256];
  }
  for (int n = wave; n < OUT_; n += 4) {
    const float* wrow = W2t + (size_t)n * FFN_;
    float s0 = 0.f, s1 = 0.f;
#pragma unroll
    for (int j = 0; j < 8; j++) {
      float4 w4 = *(const float4*)&wrow[lane * 4 + j * 256];
      s0 += w4.x * h0[j].x + w4.y * h0[j].y + w4.z * h0[j].z + w4.w * h0[j].w;
      s1 += w4.x * h1[j].x + w4.y * h1[j].y + w4.z * h1[j].z + w4.w * h1[j].w;
    }
    s0 = wred_sum(s0);
    s1 = wred_sum(s1);
    if (lane == 0) {
      out[(size_t)b0 * OUT_ + n] = s0 + b2[n];
      out[(size_t)(b0 + 1) * OUT_ + n] = s1 + b2[n];
    }
  }
}

extern "C" void kernel_launch(void* const* d_in, const int* in_sizes, int n_in,
                              void* d_out, int out_size, void* d_ws, size_t ws_size,
                              hipStream_t stream) {
  const float* lo = (const float*)d_in[0];
  const float* ro = (const float*)d_in[1];
  const float* la = (const float*)d_in[2];
  const float* ra = (const float*)d_in[3];
  const float* noise = (const float*)d_in[6];
  const float* w_i_w = (const float*)d_in[7];
  const float* w_i_b = (const float*)d_in[8];
  const float* prj_w = (const float*)d_in[9];
  const float* prj_b = (const float*)d_in[10];
  const float* W1 = (const float*)d_in[11];
  const float* b1 = (const float*)d_in[12];
  const float* W2 = (const float*)d_in[13];
  const float* b2 = (const float*)d_in[14];

  float* out = (float*)d_out;
  float* o_logits = out;                  // [1024,86]
  float* o_hout  = out + 88064;           // [1024,512]
  float* o_hpert = o_hout + 524288;       // [1024,512]
  float* o_ls    = o_hpert + 524288;      // [65536]
  float* o_rs    = o_ls + 65536;          // [65536]
  float* o_lo    = o_rs + 65536;          // [1024,512]
  float* o_ro    = o_lo + 524288;         // [1024,512]

  float* ws = (float*)d_ws;
  float* Mt   = ws; ws += 512 * 512;      // Mt[k][j] = sum_h w_i_w[k][h]*prj_w[j][h]
  float* uL   = ws; ws += B_ * H_;
  float* uR   = ws; ws += B_ * H_;
  float* pL   = ws; ws += B_ * H_;
  float* pR   = ws; ws += B_ * H_;
  float* pair = ws; ws += B_ * 2 * H_;
  float* hid  = ws; ws += B_ * FFN_;
  float* W2t  = ws; ws += OUT_ * FFN_;
  float* dv   = ws; ws += 512;
  float* ev   = ws; ws += 512;
  float* cL   = ws; ws += 1024;
  float* cR   = ws; ws += 1024;
  float* c0   = ws; ws += 4;

  k_prep<<<1025, 64, 0, stream>>>(w_i_w, w_i_b, prj_w, prj_b, dv, ev, c0);
  // Mt = w_i_w @ prj_w^T  (NT, 512x512x512)
  gemm64<true, false, false><<<dim3(8, 8), 256, 0, stream>>>(w_i_w, prj_w, nullptr, Mt, 512, 512, 512);
  // u_left = right_output @ Mt^T + d ; u_right = left_output @ Mt^T + d  (NT, 1024x512x512)
  gemm64<true, true, false><<<dim3(16, 8), 256, 0, stream>>>(ro, Mt, dv, uL, 1024, 512, 512);
  gemm64<true, true, false><<<dim3(16, 8), 256, 0, stream>>>(lo, Mt, dv, uR, 1024, 512, 512);
  k_cvec<<<dim3(1024, 2), 64, 0, stream>>>(ro, lo, ev, c0, cL, cR);
  // fused scores+softmax+pool, one pass over atom matrices
  k_atoms<<<dim3(1024, 2), 512, 0, stream>>>(la, ra, uL, uR, cL, cR, o_ls, o_rs, pL, pR);
  k_pert<<<1024, 512, 0, stream>>>(lo, ro, noise, pL, pR, o_hout, o_hpert, pair);
  // FFN1: hid = relu(pair @ W1 + b1)  (NN, 1024x2048x1024)
  gemm64<false, true, true><<<dim3(16, 32), 256, 0, stream>>>(pair, W1, b1, hid, 1024, 2048, 1024);
  k_w2t<<<688, 256, 0, stream>>>(W2, W2t);
  k_ffn2<<<512, 256, 0, stream>>>(hid, W2t, b2, o_logits);
  hipMemcpyAsync(o_lo, lo, (size_t)B_ * H_ * 4, hipMemcpyDeviceToDevice, stream);
  hipMemcpyAsync(o_ro, ro, (size_t)B_ * H_ * 4, hipMemcpyDeviceToDevice, stream);
}

// Round 2
// 189.693 us; speedup vs baseline: 1.2818x; 1.2818x over previous
//
#include <hip/hip_runtime.h>
#include <hip/hip_bf16.h>

#define B_ 1024
#define H_ 512
#define N_ (B_ * 64)
#define FFN_ 2048
#define OUT_ 86

typedef __bf16 bf16_t;
typedef __attribute__((ext_vector_type(8))) __bf16 bf16x8;
typedef __attribute__((ext_vector_type(4))) float f32x4;

__device__ __forceinline__ float wred_sum(float v) {
#pragma unroll
  for (int m = 32; m; m >>= 1) v += __shfl_xor(v, m);
  return v;
}
__device__ __forceinline__ float wred_max(float v) {
#pragma unroll
  for (int m = 32; m; m >>= 1) v = fmaxf(v, __shfl_xor(v, m));
  return v;
}

__device__ __forceinline__ void gload_lds16(const void* g, void* l) {
  __builtin_amdgcn_global_load_lds((const __attribute__((address_space(1))) unsigned int*)g,
                                   (__attribute__((address_space(3))) unsigned int*)l, 16, 0, 0);
}

// d[k] = sum_h w_i_w[k][h]*prj_b[h]; e[j] = sum_h prj_w[j][h]*w_b[h]; c0 = w_b . prj_b
__global__ void k_prep(const float* __restrict__ w_i_w, const float* __restrict__ w_i_b,
                       const float* __restrict__ prj_w, const float* __restrict__ prj_b,
                       float* __restrict__ dv, float* __restrict__ ev, float* __restrict__ c0) {
  int b = blockIdx.x, l = threadIdx.x;
  float s = 0.f;
  if (b < 512) {
    for (int h = l; h < H_; h += 64) s += w_i_w[b * H_ + h] * prj_b[h];
    s = wred_sum(s);
    if (l == 0) dv[b] = s;
  } else if (b < 1024) {
    int j = b - 512;
    for (int h = l; h < H_; h += 64) s += prj_w[j * H_ + h] * w_i_b[h];
    s = wred_sum(s);
    if (l == 0) ev[j] = s;
  } else {
    for (int h = l; h < H_; h += 64) s += w_i_b[h] * prj_b[h];
    s = wred_sum(s);
    if (l == 0) c0[0] = s;
  }
}

__global__ void k_cvec(const float* __restrict__ ro, const float* __restrict__ lo,
                       const float* __restrict__ ev, const float* __restrict__ c0,
                       float* __restrict__ cL, float* __restrict__ cR) {
  int b = blockIdx.x, side = blockIdx.y, l = threadIdx.x;
  const float* x = side ? lo : ro;
  float s = 0.f;
  for (int j = l; j < H_; j += 64) s += x[b * H_ + j] * ev[j];
  s = wred_sum(s);
  if (l == 0) (side ? cR : cL)[b] = s + c0[0];
}

// Generic f32 tiled GEMM (kept for the small score-path GEMMs, f32 for accuracy)
template <bool BT, bool BIAS, bool RELU>
__global__ __launch_bounds__(256) void gemm64(const float* __restrict__ A, const float* __restrict__ Bm,
                                              const float* __restrict__ bias, float* __restrict__ C,
                                              int M, int N, int K) {
  __shared__ float As[16][68];
  __shared__ float Bs[16][68];
  const int bm = blockIdx.x * 64, bn = blockIdx.y * 64;
  const int t = threadIdx.x;
  const int tx = t & 15, ty = t >> 4;
  float acc[4][4] = {};
  for (int k0 = 0; k0 < K; k0 += 16) {
#pragma unroll
    for (int i = 0; i < 4; i++) {
      int m = (t >> 4) + i * 16;
      As[t & 15][m] = A[(size_t)(bm + m) * K + k0 + (t & 15)];
    }
    if (BT) {
#pragma unroll
      for (int i = 0; i < 4; i++) {
        int n = (t >> 4) + i * 16;
        Bs[t & 15][n] = Bm[(size_t)(bn + n) * K + k0 + (t & 15)];
      }
    } else {
#pragma unroll
      for (int i = 0; i < 4; i++) {
        int kk = (t >> 6) + i * 4;
        Bs[kk][t & 63] = Bm[(size_t)(k0 + kk) * N + bn + (t & 63)];
      }
    }
    __syncthreads();
#pragma unroll
    for (int kk = 0; kk < 16; kk++) {
      float4 av = *(const float4*)&As[kk][ty * 4];
      float4 bv = *(const float4*)&Bs[kk][tx * 4];
      float a_[4] = {av.x, av.y, av.z, av.w};
      float b_[4] = {bv.x, bv.y, bv.z, bv.w};
#pragma unroll
      for (int i = 0; i < 4; i++)
#pragma unroll
        for (int j = 0; j < 4; j++) acc[i][j] += a_[i] * b_[j];
    }
    __syncthreads();
  }
#pragma unroll
  for (int i = 0; i < 4; i++) {
    int m = bm + ty * 4 + i;
    float tmp[4];
#pragma unroll
    for (int j = 0; j < 4; j++) {
      float x = acc[i][j];
      if (BIAS) x += bias[bn + tx * 4 + j];
      if (RELU) x = fmaxf(x, 0.f);
      tmp[j] = x;
    }
    float4 v;
    v.x = tmp[0]; v.y = tmp[1]; v.z = tmp[2]; v.w = tmp[3];
    *(float4*)&C[(size_t)m * N + bn + tx * 4] = v;
  }
}

// Fused scores+softmax+pool; register-resident 64x512 tile.
// __launch_bounds__(512,2): allow ~256 VGPRs so a[8][8] stays in registers and
// all 16 float4 loads issue before any use (prev build: 44 VGPRs => serialized).
__global__ __launch_bounds__(512, 2) void k_atoms(const float* __restrict__ atomL, const float* __restrict__ atomR,
                                                  const float* __restrict__ uL, const float* __restrict__ uR,
                                                  const float* __restrict__ cL, const float* __restrict__ cR,
                                                  float* __restrict__ scoresL, float* __restrict__ scoresR,
                                                  float* __restrict__ pL, float* __restrict__ pR) {
  const int b = blockIdx.x, side = blockIdx.y;
  const float* __restrict__ atom = side ? atomR : atomL;
  const float* __restrict__ u = side ? uR : uL;
  const float cb = (side ? cR : cL)[b];
  float* __restrict__ scores = side ? scoresR : scoresL;
  float* __restrict__ p = side ? pR : pL;

  const int t = threadIdx.x, wave = t >> 6, lane = t & 63;
  const int colA = lane * 4, colB = 256 + lane * 4;

  __shared__ float s_lds[64];
  __shared__ float pp_lds[8][512];

  float a[8][8];
  float ur[8];
  const float* base = atom + ((size_t)b * 64 + wave * 8) * H_;
  // issue ALL tile loads first (independent, deep MLP)
#pragma unroll
  for (int ai = 0; ai < 8; ai++) {
    *(float4*)&a[ai][0] = *(const float4*)&base[(size_t)ai * H_ + colA];
    *(float4*)&a[ai][4] = *(const float4*)&base[(size_t)ai * H_ + colB];
  }
  *(float4*)&ur[0] = *(const float4*)&u[(size_t)b * H_ + colA];
  *(float4*)&ur[4] = *(const float4*)&u[(size_t)b * H_ + colB];

#pragma unroll
  for (int ai = 0; ai < 8; ai++) {
    float dot = 0.f;
#pragma unroll
    for (int j = 0; j < 8; j++) dot += a[ai][j] * ur[j];
    dot = wred_sum(dot);
    if (lane == 0) s_lds[wave * 8 + ai] = dot + cb;
  }
  __syncthreads();
  if (wave == 0) {
    float s = s_lds[lane];
    float mx = wred_max(s);
    float e = expf(s - mx);
    float z = wred_sum(e);
    float w = e / z;
    s_lds[lane] = w;
    scores[(size_t)b * 64 + lane] = w;
  }
  __syncthreads();
  float pp[8] = {};
#pragma unroll
  for (int ai = 0; ai < 8; ai++) {
    float w = s_lds[wave * 8 + ai];
#pragma unroll
    for (int j = 0; j < 8; j++) pp[j] += w * a[ai][j];
  }
#pragma unroll
  for (int j = 0; j < 4; j++) {
    pp_lds[wave][colA + j] = pp[j];
    pp_lds[wave][colB + j] = pp[4 + j];
  }
  __syncthreads();
  float s = 0.f;
#pragma unroll
  for (int w2 = 0; w2 < 8; w2++) s += pp_lds[w2][t];
  p[(size_t)b * H_ + t] = s;
}

// perturbation + bf16 pair assembly
__global__ __launch_bounds__(512) void k_pert(const float* __restrict__ lo, const float* __restrict__ ro,
                                              const float* __restrict__ noise,
                                              const float* __restrict__ pL, const float* __restrict__ pR,
                                              float* __restrict__ h_out, float* __restrict__ h_pert,
                                              bf16_t* __restrict__ pairbf) {
  const int b = blockIdx.x, t = threadIdx.x;
  float nv = noise[(size_t)b * H_ + t];
  float sq = nv * nv;
  sq = wred_sum(sq);
  __shared__ float red[8];
  if ((t & 63) == 0) red[t >> 6] = sq;
  __syncthreads();
  float tot = 0.f;
#pragma unroll
  for (int i = 0; i < 8; i++) tot += red[i];
  float nrm = fmaxf(sqrtf(tot), 1e-12f);
  float nn = nv / nrm * 0.1f;
  float h = ro[(size_t)b * H_ + t] * pL[(size_t)b * H_ + t];
  float tt = lo[(size_t)b * H_ + t] * pR[(size_t)b * H_ + t];
  float sh = (h > 0.f) ? 1.f : ((h < 0.f) ? -1.f : 0.f);
  float st = (tt > 0.f) ? 1.f : ((tt < 0.f) ? -1.f : 0.f);
  float hp = h + sh * nn;
  float tp = tt + st * nn;
  h_out[(size_t)b * H_ + t] = h;
  h_pert[(size_t)b * H_ + t] = hp;
  pairbf[(size_t)b * 1024 + t] = (bf16_t)hp;
  pairbf[(size_t)b * 1024 + 512 + t] = (bf16_t)tp;
}

// W1 [1024][2048] f32 -> W1t [2048][1024] bf16 (transpose + cast, LDS tiled)
__global__ __launch_bounds__(256) void k_w1t(const float* __restrict__ W1, bf16_t* __restrict__ W1t) {
  __shared__ float tile[32][33];
  const int bx = blockIdx.x;  // n tile (2048/32)
  const int by = blockIdx.y;  // k tile (1024/32)
  const int tx = threadIdx.x & 31, ty = threadIdx.x >> 5;
#pragma unroll
  for (int i = ty; i < 32; i += 8)
    tile[i][tx] = W1[(size_t)(by * 32 + i) * FFN_ + bx * 32 + tx];
  __syncthreads();
#pragma unroll
  for (int i = ty; i < 32; i += 8)
    W1t[(size_t)(bx * 32 + i) * 1024 + by * 32 + tx] = (bf16_t)tile[tx][i];
}

// FFN1 via MFMA bf16: hid[1024][2048] = relu(pair[1024][1024] @ W1 + b1)
// A = pairbf [M][K] bf16, Bt = W1t [N][K] bf16. 64x64 tile, BK=64, 4 waves (2x2).
// LDS linear (global_load_lds), XOR-swizzled SOURCE + matching swizzled READ (rule #21).
__global__ __launch_bounds__(256) void k_ffn1(const bf16_t* __restrict__ Abf, const bf16_t* __restrict__ Bt,
                                              const float* __restrict__ bias, float* __restrict__ C) {
  __shared__ bf16_t As[64 * 64];
  __shared__ bf16_t Bs[64 * 64];
  const int bm = blockIdx.x * 64, bn = blockIdx.y * 64;
  const int t = threadIdx.x;
  const int lane = t & 63, wave = t >> 6;
  const int wm = wave & 1, wn = wave >> 1;
  const int l15 = lane & 15, l4 = lane >> 4;
  f32x4 acc[2][2] = {{{0.f, 0.f, 0.f, 0.f}, {0.f, 0.f, 0.f, 0.f}},
                     {{0.f, 0.f, 0.f, 0.f}, {0.f, 0.f, 0.f, 0.f}}};

  for (int k0 = 0; k0 < 1024; k0 += 64) {
#pragma unroll
    for (int r = 0; r < 2; r++) {
      const int off = (r * 256 + t) * 16;  // linear byte offset in 8KB tile
      const int row = off >> 7;            // 128B per row (64 bf16)
      const int g = (off >> 4) & 7;        // 16B granule within row
      const int scb = ((g ^ (row & 7)) << 4);  // pre-swizzled source granule
      gload_lds16((const char*)Abf + (size_t)(bm + row) * 2048 + k0 * 2 + scb, (char*)As + off);
      gload_lds16((const char*)Bt + (size_t)(bn + row) * 2048 + k0 * 2 + scb, (char*)Bs + off);
    }
    __syncthreads();
#pragma unroll
    for (int ks = 0; ks < 2; ks++) {
      const int ar0 = wm * 32 + l15, ar1 = ar0 + 16;
      const int br0 = wn * 32 + l15, br1 = br0 + 16;
      const int gA = ks * 4 + l4;
      bf16x8 a0 = *(const bf16x8*)((const char*)As + ar0 * 128 + ((gA ^ (ar0 & 7)) << 4));
      bf16x8 a1 = *(const bf16x8*)((const char*)As + ar1 * 128 + ((gA ^ (ar1 & 7)) << 4));
      bf16x8 b0 = *(const bf16x8*)((const char*)Bs + br0 * 128 + ((gA ^ (br0 & 7)) << 4));
      bf16x8 b1 = *(const bf16x8*)((const char*)Bs + br1 * 128 + ((gA ^ (br1 & 7)) << 4));
      acc[0][0] = __builtin_amdgcn_mfma_f32_16x16x32_bf16(a0, b0, acc[0][0], 0, 0, 0);
      acc[0][1] = __builtin_amdgcn_mfma_f32_16x16x32_bf16(a0, b1, acc[0][1], 0, 0, 0);
      acc[1][0] = __builtin_amdgcn_mfma_f32_16x16x32_bf16(a1, b0, acc[1][0], 0, 0, 0);
      acc[1][1] = __builtin_amdgcn_mfma_f32_16x16x32_bf16(a1, b1, acc[1][1], 0, 0, 0);
    }
    __syncthreads();
  }
#pragma unroll
  for (int mi = 0; mi < 2; mi++)
#pragma unroll
    for (int nj = 0; nj < 2; nj++)
#pragma unroll
      for (int r = 0; r < 4; r++) {
        const int m = bm + wm * 32 + mi * 16 + l4 * 4 + r;
        const int n = bn + wn * 32 + nj * 16 + l15;
        float v = acc[mi][nj][r] + bias[n];
        C[(size_t)m * FFN_ + n] = fmaxf(v, 0.f);
      }
}

__global__ void k_w2t(const float* __restrict__ W2, float* __restrict__ W2t) {
  int idx = blockIdx.x * 256 + threadIdx.x;
  if (idx < OUT_ * FFN_) {
    int n = idx / FFN_, k = idx % FFN_;
    W2t[idx] = W2[(size_t)k * OUT_ + n];
  }
}

__global__ __launch_bounds__(256) void k_ffn2(const float* __restrict__ hid, const float* __restrict__ W2t,
                                              const float* __restrict__ b2, float* __restrict__ out) {
  const int b0 = blockIdx.x * 2;
  const int t = threadIdx.x, wave = t >> 6, lane = t & 63;
  float4 h0[8], h1[8];
  const float* r0 = hid + (size_t)b0 * FFN_;
#pragma unroll
  for (int j = 0; j < 8; j++) {
    h0[j] = *(const float4*)&r0[lane * 4 + j * 256];
    h1[j] = *(const float4*)&r0[FFN_ + lane * 4 + j * 256];
  }
  for (int n = wave; n < OUT_; n += 4) {
    const float* wrow = W2t + (size_t)n * FFN_;
    float s0 = 0.f, s1 = 0.f;
#pragma unroll
    for (int j = 0; j < 8; j++) {
      float4 w4 = *(const float4*)&wrow[lane * 4 + j * 256];
      s0 += w4.x * h0[j].x + w4.y * h0[j].y + w4.z * h0[j].z + w4.w * h0[j].w;
      s1 += w4.x * h1[j].x + w4.y * h1[j].y + w4.z * h1[j].z + w4.w * h1[j].w;
    }
    s0 = wred_sum(s0);
    s1 = wred_sum(s1);
    if (lane == 0) {
      out[(size_t)b0 * OUT_ + n] = s0 + b2[n];
      out[(size_t)(b0 + 1) * OUT_ + n] = s1 + b2[n];
    }
  }
}

extern "C" void kernel_launch(void* const* d_in, const int* in_sizes, int n_in,
                              void* d_out, int out_size, void* d_ws, size_t ws_size,
                              hipStream_t stream) {
  const float* lo = (const float*)d_in[0];
  const float* ro = (const float*)d_in[1];
  const float* la = (const float*)d_in[2];
  const float* ra = (const float*)d_in[3];
  const float* noise = (const float*)d_in[6];
  const float* w_i_w = (const float*)d_in[7];
  const float* w_i_b = (const float*)d_in[8];
  const float* prj_w = (const float*)d_in[9];
  const float* prj_b = (const float*)d_in[10];
  const float* W1 = (const float*)d_in[11];
  const float* b1 = (const float*)d_in[12];
  const float* W2 = (const float*)d_in[13];
  const float* b2 = (const float*)d_in[14];

  float* out = (float*)d_out;
  float* o_logits = out;                  // [1024,86]
  float* o_hout  = out + 88064;           // [1024,512]
  float* o_hpert = o_hout + 524288;       // [1024,512]
  float* o_ls    = o_hpert + 524288;      // [65536]
  float* o_rs    = o_ls + 65536;          // [65536]
  float* o_lo    = o_rs + 65536;          // [1024,512]
  float* o_ro    = o_lo + 524288;         // [1024,512]

  float* ws = (float*)d_ws;
  float* Mt   = ws; ws += 512 * 512;
  float* uL   = ws; ws += B_ * H_;
  float* uR   = ws; ws += B_ * H_;
  float* pL   = ws; ws += B_ * H_;
  float* pR   = ws; ws += B_ * H_;
  float* hid  = ws; ws += B_ * FFN_;
  float* W2t  = ws; ws += OUT_ * FFN_;
  bf16_t* pairbf = (bf16_t*)ws; ws += B_ * 1024 / 2;   // [1024][1024] bf16
  bf16_t* W1t    = (bf16_t*)ws; ws += FFN_ * 1024 / 2; // [2048][1024] bf16
  float* dv   = ws; ws += 512;
  float* ev   = ws; ws += 512;
  float* cL   = ws; ws += 1024;
  float* cR   = ws; ws += 1024;
  float* c0   = ws; ws += 4;

  k_prep<<<1025, 64, 0, stream>>>(w_i_w, w_i_b, prj_w, prj_b, dv, ev, c0);
  gemm64<true, false, false><<<dim3(8, 8), 256, 0, stream>>>(w_i_w, prj_w, nullptr, Mt, 512, 512, 512);
  gemm64<true, true, false><<<dim3(16, 8), 256, 0, stream>>>(ro, Mt, dv, uL, 1024, 512, 512);
  gemm64<true, true, false><<<dim3(16, 8), 256, 0, stream>>>(lo, Mt, dv, uR, 1024, 512, 512);
  k_cvec<<<dim3(1024, 2), 64, 0, stream>>>(ro, lo, ev, c0, cL, cR);
  k_w1t<<<dim3(64, 32), 256, 0, stream>>>(W1, W1t);  // overlappable prep
  k_atoms<<<dim3(1024, 2), 512, 0, stream>>>(la, ra, uL, uR, cL, cR, o_ls, o_rs, pL, pR);
  k_pert<<<1024, 512, 0, stream>>>(lo, ro, noise, pL, pR, o_hout, o_hpert, pairbf);
  k_ffn1<<<dim3(16, 32), 256, 0, stream>>>(pairbf, W1t, b1, hid);
  k_w2t<<<688, 256, 0, stream>>>(W2, W2t);
  k_ffn2<<<512, 256, 0, stream>>>(hid, W2t, b2, o_logits);
  hipMemcpyAsync(o_lo, lo, (size_t)B_ * H_ * 4, hipMemcpyDeviceToDevice, stream);
  hipMemcpyAsync(o_ro, ro, (size_t)B_ * H_ * 4, hipMemcpyDeviceToDevice, stream);
}